// Round 1
// baseline (179.262 us; speedup 1.0000x reference)
//
#include <hip/hip_runtime.h>
#include <hip/hip_bf16.h>

typedef __bf16 bf16_t;
typedef __attribute__((ext_vector_type(8))) __bf16 bf16x8;
typedef __attribute__((ext_vector_type(4))) float f32x4;

#define AS1 __attribute__((address_space(1)))
#define AS3 __attribute__((address_space(3)))

__device__ __forceinline__ void gload_lds16(const void* g, void* l) {
  __builtin_amdgcn_global_load_lds((const AS1 void*)g, (AS3 void*)l, 16, 0, 0);
}

// ---------------- prep: weight transpose fp32 [K][N] -> bf16 [N][K] ----------------
__global__ void __launch_bounds__(256) transpose_w_kernel(const float* __restrict__ w,
                                                          bf16_t* __restrict__ wT) {
  __shared__ float tile[32][33];
  const int tx = threadIdx.x, ty = threadIdx.y;
  const int k0 = blockIdx.x * 32, n0 = blockIdx.y * 32;
#pragma unroll
  for (int i = 0; i < 32; i += 8)
    tile[ty + i][tx] = w[(k0 + ty + i) * 512 + n0 + tx];
  __syncthreads();
#pragma unroll
  for (int i = 0; i < 32; i += 8)
    wT[(n0 + ty + i) * 512 + k0 + tx] = (bf16_t)tile[tx][ty + i];
}

// ---------------- prep: x [B][C][S] fp32 -> xr [B][S][C] bf16 ----------------
__global__ void __launch_bounds__(256) transpose_x_kernel(const float* __restrict__ x,
                                                          bf16_t* __restrict__ xr) {
  __shared__ float tile[32][33];
  const int tx = threadIdx.x, ty = threadIdx.y;
  const int b = blockIdx.z;
  const int s0 = blockIdx.x * 32, c0 = blockIdx.y * 32;
  const float* xb = x + (size_t)b * 512 * 1024;
#pragma unroll
  for (int i = 0; i < 32; i += 8)
    tile[ty + i][tx] = xb[(c0 + ty + i) * 1024 + s0 + tx];  // tile[c][s]
  __syncthreads();
  bf16_t* xrb = xr + (size_t)b * 1024 * 512;
#pragma unroll
  for (int i = 0; i < 32; i += 8)
    xrb[(s0 + ty + i) * 512 + c0 + tx] = (bf16_t)tile[tx][ty + i];
}

// ---------------- prep: v [BH][S][64] bf16 -> vt [BH][64][S] bf16 ----------------
__global__ void __launch_bounds__(256) transpose_v_kernel(const bf16_t* __restrict__ v,
                                                          bf16_t* __restrict__ vt) {
  __shared__ bf16_t tile[32][33];
  const int tx = threadIdx.x, ty = threadIdx.y;
  const int bh = blockIdx.z;
  const int s0 = blockIdx.x * 32, d0 = blockIdx.y * 32;
  const bf16_t* vb = v + (size_t)bh * 1024 * 64;
#pragma unroll
  for (int i = 0; i < 32; i += 8)
    tile[ty + i][tx] = vb[(s0 + ty + i) * 64 + d0 + tx];  // tile[s][d]
  __syncthreads();
  bf16_t* vtb = vt + (size_t)bh * 64 * 1024;
#pragma unroll
  for (int i = 0; i < 32; i += 8)
    vtb[(d0 + ty + i) * 1024 + s0 + tx] = tile[tx][ty + i];
}

// ---------------- shared 128x128xK NT-GEMM mainloop (A[M][K], B[N][K], both bf16) ----
__device__ __forceinline__ void gemm_nt_128x128(const bf16_t* __restrict__ Abase,
                                                const bf16_t* __restrict__ Bbase,
                                                int K, bf16_t* As, bf16_t* Bs,
                                                f32x4 acc[4][4]) {
  const int tid = threadIdx.x;
  const int lane = tid & 63;
  const int wid = tid >> 6;
  const int wr = wid >> 1, wc = wid & 1;
  const int lrow = lane & 15;
  const int kgrp = lane >> 4;
  const int r0 = tid >> 2;             // 0..63: row within 64-row chunk
  const int cb = (tid & 3) * 16;       // byte offset within 64B row

  for (int kt = 0; kt < K; kt += 32) {
#pragma unroll
    for (int j = 0; j < 2; ++j) {
      int row = j * 64 + r0;
      gload_lds16((const char*)(Abase + row * K + kt) + cb, (char*)As + row * 64 + cb);
    }
#pragma unroll
    for (int j = 0; j < 2; ++j) {
      int row = j * 64 + r0;
      gload_lds16((const char*)(Bbase + row * K + kt) + cb, (char*)Bs + row * 64 + cb);
    }
    __syncthreads();
    bf16x8 a[4], b[4];
#pragma unroll
    for (int mf = 0; mf < 4; ++mf)
      a[mf] = *(const bf16x8*)(As + (wr * 64 + mf * 16 + lrow) * 32 + kgrp * 8);
#pragma unroll
    for (int nf = 0; nf < 4; ++nf)
      b[nf] = *(const bf16x8*)(Bs + (wc * 64 + nf * 16 + lrow) * 32 + kgrp * 8);
#pragma unroll
    for (int mf = 0; mf < 4; ++mf)
#pragma unroll
      for (int nf = 0; nf < 4; ++nf)
        acc[mf][nf] = __builtin_amdgcn_mfma_f32_16x16x32_bf16(a[mf], b[nf], acc[mf][nf], 0, 0, 0);
    __syncthreads();
  }
}

// ---------------- QKV projection: xr[8192][512] @ wT[512][512]^T -> q/k/v [BH][S][64]
__global__ void __launch_bounds__(256) gemm_qkv_kernel(
    const bf16_t* __restrict__ xr, const bf16_t* __restrict__ wqT,
    const bf16_t* __restrict__ wkT, const bf16_t* __restrict__ wvT,
    const float* __restrict__ bq, const float* __restrict__ bk,
    const float* __restrict__ bv, bf16_t* __restrict__ qo, bf16_t* __restrict__ ko,
    bf16_t* __restrict__ vo) {
  __shared__ bf16_t As[128 * 32];
  __shared__ bf16_t Bs[128 * 32];
  const int bn = blockIdx.x, bm = blockIdx.y, z = blockIdx.z;
  const bf16_t* wT = (z == 0) ? wqT : (z == 1) ? wkT : wvT;
  const float* bias = (z == 0) ? bq : (z == 1) ? bk : bv;
  bf16_t* out = (z == 0) ? qo : (z == 1) ? ko : vo;
  f32x4 acc[4][4] = {};
  gemm_nt_128x128(xr + bm * 128 * 512, wT + bn * 128 * 512, 512, As, Bs, acc);
  const int lane = threadIdx.x & 63, wid = threadIdx.x >> 6;
  const int wr = wid >> 1, wc = wid & 1;
  const int row0 = bm * 128 + wr * 64;
  const int col0 = bn * 128 + wc * 64;
#pragma unroll
  for (int mf = 0; mf < 4; ++mf)
#pragma unroll
    for (int nf = 0; nf < 4; ++nf) {
      int n = col0 + nf * 16 + (lane & 15);
      int h = n >> 6, d = n & 63;
      float bb = bias[n];
#pragma unroll
      for (int r = 0; r < 4; ++r) {
        int m = row0 + mf * 16 + (lane >> 4) * 4 + r;
        int b = m >> 10, s = m & 1023;
        out[((b * 8 + h) * 1024 + s) * 64 + d] = (bf16_t)(acc[mf][nf][r] + bb);
      }
    }
}

// ---------------- flash attention: per (b,h), 64 q-rows per block ----------------
__global__ void __launch_bounds__(256) attn_kernel(const bf16_t* __restrict__ q,
                                                   const bf16_t* __restrict__ k,
                                                   const bf16_t* __restrict__ vt,
                                                   bf16_t* __restrict__ attn_out) {
  __shared__ bf16_t Pl[4][16][72];  // per-wave P tile, +8 bf16 pad per row
  const int tid = threadIdx.x;
  const int lane = tid & 63, wid = tid >> 6;
  const int lrow = lane & 15, kgrp = lane >> 4;
  const int bh = blockIdx.y, qb = blockIdx.x;
  const int b = bh >> 3, h = bh & 7;

  const bf16_t* qh = q + (size_t)bh * 1024 * 64;
  const bf16_t* kh = k + (size_t)bh * 1024 * 64;
  const bf16_t* vth = vt + (size_t)bh * 64 * 1024;

  const int qrow = qb * 64 + wid * 16 + lrow;
  bf16x8 qa[2];
  qa[0] = *(const bf16x8*)(qh + qrow * 64 + kgrp * 8);
  qa[1] = *(const bf16x8*)(qh + qrow * 64 + 32 + kgrp * 8);

  float m_run[4], l_run[4];
  f32x4 o[4] = {};
#pragma unroll
  for (int r = 0; r < 4; ++r) { m_run[r] = -1e30f; l_run[r] = 0.f; }
  const float scale = 0.044194173824159216f;  // 1/sqrt(512)

  for (int kb = 0; kb < 16; ++kb) {
    f32x4 sa[4] = {};
#pragma unroll
    for (int nf = 0; nf < 4; ++nf) {
      int key = kb * 64 + nf * 16 + lrow;
      bf16x8 b0 = *(const bf16x8*)(kh + key * 64 + kgrp * 8);
      bf16x8 b1 = *(const bf16x8*)(kh + key * 64 + 32 + kgrp * 8);
      sa[nf] = __builtin_amdgcn_mfma_f32_16x16x32_bf16(qa[0], b0, sa[nf], 0, 0, 0);
      sa[nf] = __builtin_amdgcn_mfma_f32_16x16x32_bf16(qa[1], b1, sa[nf], 0, 0, 0);
    }
#pragma unroll
    for (int r = 0; r < 4; ++r) {
      float mx = fmaxf(fmaxf(sa[0][r], sa[1][r]), fmaxf(sa[2][r], sa[3][r]));
#pragma unroll
      for (int off = 1; off < 16; off <<= 1)
        mx = fmaxf(mx, __shfl_xor(mx, off, 64));
      mx *= scale;
      float m_new = fmaxf(m_run[r], mx);
      float alpha = __expf(m_run[r] - m_new);
      float rs = 0.f;
#pragma unroll
      for (int nf = 0; nf < 4; ++nf) {
        float p = __expf(sa[nf][r] * scale - m_new);
        sa[nf][r] = p;
        rs += p;
      }
#pragma unroll
      for (int off = 1; off < 16; off <<= 1)
        rs += __shfl_xor(rs, off, 64);
      l_run[r] = l_run[r] * alpha + rs;
      m_run[r] = m_new;
      o[0][r] *= alpha; o[1][r] *= alpha; o[2][r] *= alpha; o[3][r] *= alpha;
    }
#pragma unroll
    for (int nf = 0; nf < 4; ++nf)
#pragma unroll
      for (int r = 0; r < 4; ++r)
        Pl[wid][kgrp * 4 + r][nf * 16 + lrow] = (bf16_t)sa[nf][r];
    asm volatile("s_waitcnt lgkmcnt(0)" ::: "memory");
    __builtin_amdgcn_sched_barrier(0);
#pragma unroll
    for (int kk = 0; kk < 2; ++kk) {
      bf16x8 pa = *(const bf16x8*)(&Pl[wid][lrow][kk * 32 + kgrp * 8]);
#pragma unroll
      for (int nfo = 0; nfo < 4; ++nfo) {
        bf16x8 vb = *(const bf16x8*)(vth + (nfo * 16 + lrow) * 1024 + kb * 64 + kk * 32 + kgrp * 8);
        o[nfo] = __builtin_amdgcn_mfma_f32_16x16x32_bf16(pa, vb, o[nfo], 0, 0, 0);
      }
    }
    asm volatile("s_waitcnt lgkmcnt(0)" ::: "memory");
  }
#pragma unroll
  for (int r = 0; r < 4; ++r) {
    float inv = 1.0f / l_run[r];
    int s = qb * 64 + wid * 16 + kgrp * 4 + r;
#pragma unroll
    for (int nfo = 0; nfo < 4; ++nfo) {
      int d = nfo * 16 + lrow;
      attn_out[((b * 1024 + s) * 8 + h) * 64 + d] = (bf16_t)(o[nfo][r] * inv);
    }
  }
}

// ---------------- out-proj (transposed): woT[512][512] x attn[8192][512] + x -> out
__global__ void __launch_bounds__(256) gemm_out_kernel(const bf16_t* __restrict__ woT,
                                                       const bf16_t* __restrict__ attn,
                                                       const float* __restrict__ x,
                                                       const float* __restrict__ bo,
                                                       float* __restrict__ out) {
  __shared__ bf16_t As[128 * 32];
  __shared__ bf16_t Bs[128 * 32];
  const int bn = blockIdx.x, bm = blockIdx.y;
  f32x4 acc[4][4] = {};
  gemm_nt_128x128(woT + bm * 128 * 512, attn + bn * 128 * 512, 512, As, Bs, acc);
  const int lane = threadIdx.x & 63, wid = threadIdx.x >> 6;
  const int wr = wid >> 1, wc = wid & 1;
  const int c0 = bm * 128 + wr * 64;
  const int s0g = bn * 128 + wc * 64;
#pragma unroll
  for (int mf = 0; mf < 4; ++mf)
#pragma unroll
    for (int r = 0; r < 4; ++r) {
      int c = c0 + mf * 16 + (lane >> 4) * 4 + r;
      float bias = bo[c];
#pragma unroll
      for (int nf = 0; nf < 4; ++nf) {
        int n = s0g + nf * 16 + (lane & 15);
        int b = n >> 10, s = n & 1023;
        int idx = (b * 512 + c) * 1024 + s;
        out[idx] = x[idx] + acc[mf][nf][r] + bias;
      }
    }
}

extern "C" void kernel_launch(void* const* d_in, const int* in_sizes, int n_in,
                              void* d_out, int out_size, void* d_ws, size_t ws_size,
                              hipStream_t stream) {
  const float* x  = (const float*)d_in[0];
  const float* wq = (const float*)d_in[1];
  const float* bq = (const float*)d_in[2];
  const float* wk = (const float*)d_in[3];
  const float* bk = (const float*)d_in[4];
  const float* wv = (const float*)d_in[5];
  const float* bv = (const float*)d_in[6];
  const float* wo = (const float*)d_in[7];
  const float* bo = (const float*)d_in[8];
  float* out = (float*)d_out;

  char* ws = (char*)d_ws;
  const size_t SZ_XR = (size_t)8192 * 512 * 2;   // 8 MB
  const size_t SZ_W  = (size_t)512 * 512 * 2;    // 0.5 MB
  const size_t SZ_T  = (size_t)8 * 8 * 1024 * 64 * 2;  // 8 MB
  bf16_t* xr   = (bf16_t*)(ws);                       // [0, 8MB) — free after QKV GEMM
  bf16_t* wqT  = (bf16_t*)(ws + SZ_XR);
  bf16_t* wkT  = (bf16_t*)(ws + SZ_XR + SZ_W);
  bf16_t* wvT  = (bf16_t*)(ws + SZ_XR + 2 * SZ_W);
  bf16_t* woT  = (bf16_t*)(ws + SZ_XR + 3 * SZ_W);
  bf16_t* qd   = (bf16_t*)(ws + SZ_XR + 4 * SZ_W);
  bf16_t* kd   = (bf16_t*)(ws + SZ_XR + 4 * SZ_W + SZ_T);
  bf16_t* vd   = (bf16_t*)(ws + SZ_XR + 4 * SZ_W + 2 * SZ_T);
  bf16_t* vtd  = (bf16_t*)(ws);                       // alias xr (free by then)
  bf16_t* attn = (bf16_t*)(ws + SZ_XR + 4 * SZ_W + 2 * SZ_T);  // alias vd (free after transpose)
  // NOTE: vd is consumed by transpose_v before attn (aliased) is written.

  dim3 tb(32, 8);
  transpose_w_kernel<<<dim3(16, 16), tb, 0, stream>>>(wq, wqT);
  transpose_w_kernel<<<dim3(16, 16), tb, 0, stream>>>(wk, wkT);
  transpose_w_kernel<<<dim3(16, 16), tb, 0, stream>>>(wv, wvT);
  transpose_w_kernel<<<dim3(16, 16), tb, 0, stream>>>(wo, woT);
  transpose_x_kernel<<<dim3(32, 16, 8), tb, 0, stream>>>(x, xr);
  gemm_qkv_kernel<<<dim3(4, 64, 3), 256, 0, stream>>>(xr, wqT, wkT, wvT, bq, bk, bv,
                                                      qd, kd, vd);
  transpose_v_kernel<<<dim3(32, 2, 64), tb, 0, stream>>>(vd, vtd);
  attn_kernel<<<dim3(16, 64), 256, 0, stream>>>(qd, kd, vtd, attn);
  gemm_out_kernel<<<dim3(64, 4), 256, 0, stream>>>(woT, attn, x, bo, out);
}